// Round 12
// baseline (336.283 us; speedup 1.0000x reference)
//
#include <hip/hip_runtime.h>
#include <stdint.h>

#define N_PTS 131072
#define RH    352
#define SREV  4.774648292756860f   /* 30 / (2*pi) */

typedef short  bf16x8 __attribute__((ext_vector_type(8)));
typedef float  f32x16 __attribute__((ext_vector_type(16)));

// ---------------- helpers ----------------
__device__ __forceinline__ unsigned short f2bf(float f) {
  uint32_t u = __builtin_bit_cast(uint32_t, f);
  u = (u + 0x7FFFu + ((u >> 16) & 1u)) >> 16;
  return (unsigned short)u;
}
__device__ __forceinline__ float bf2f(unsigned short s) {
  return __builtin_bit_cast(float, ((uint32_t)s) << 16);
}
__device__ __forceinline__ float vsin1(float x) {   // sin(2*pi*x)
  float xf = x - floorf(x);
  float r;
  asm("v_sin_f32 %0, %1" : "=v"(r) : "v"(xf));
  return r;
}
__device__ __forceinline__ f32x16 mfma_bf16(bf16x8 a, bf16x8 b, f32x16 c) {
  return __builtin_amdgcn_mfma_f32_32x32x16_bf16(a, b, c, 0, 0, 0);
}

// opaque async weight load: compiler cannot sink or track it
#define AWLOAD(d0, d1, addr64) \
  asm volatile("global_load_dwordx4 %0, %2, off\n\t" \
               "global_load_dwordx4 %1, %2, off offset:1024" \
               : "=&v"(d0), "=&v"(d1) : "v"(addr64))

// counted wait; register ties order the dependent MFMAs without sched_barrier
#define VWAIT(N, r0, r1) \
  asm volatile("s_waitcnt vmcnt(" #N ")" : "+v"(r0), "+v"(r1))

// ---------------- K0: fused pack (blocks 0..568) + router (blocks 569..824) ----
// pack: weights -> bf16 MFMA A-fragment layout.
// A-frag (32x32x16): lane l holds A[j = jb*32+(l&31)][k = kb*16 + (l>>5)*8 + i].
// Slice kb = 8 jb * 1KB contiguous. Slice 16 = bias hi/lo (k-slots 0,1) with B=1.
// router: f32 logits + exact f64 fallback when top-2 boundary gap < 1e-3
// (decision function identical to the proven all-f64 router).
__global__ __launch_bounds__(512) void setup_kernel(
    const float* __restrict__ W0, const float* __restrict__ b0,
    const float* __restrict__ Wh, const float* __restrict__ bh,
    const float* __restrict__ Wo, const float* __restrict__ bo,
    const float* __restrict__ Wd1, const float* __restrict__ bd1,
    short* __restrict__ pW0, short* __restrict__ pWh,
    short* __restrict__ pWo, short* __restrict__ pWd1,
    const float* __restrict__ ctx, const float* __restrict__ Wr1,
    const float* __restrict__ br1, const float* __restrict__ Wr2,
    const float* __restrict__ br2, uint4* __restrict__ topk,
    uint32_t* __restrict__ counts)
{
  __shared__ float w1f[RH*4];
  __shared__ float w2f[RH*8];
  __shared__ uint32_t lcnt[8];
  int b = blockIdx.x, tid = threadIdx.x;

  if (b < 569) {                        // ---------------- pack ----------------
    int jb = tid >> 6, l = tid & 63;
    int j  = jb*32 + (l & 31);
    int s0 = (l >> 5) * 8;
    unsigned short o[8];
    short* dp;
    if (b < 544) {
      int m = b / 17, slice = b % 17;
      int e = m >> 2, t = m & 3;
      const float* src; const float* bias; float scale; short* dst;
      if (t < 3) { src = Wh + (size_t)(e*3+t)*65536; bias = bh + (size_t)(e*3+t)*256; scale = SREV; dst = pWh + (size_t)(e*3+t)*69632; }
      else       { src = Wo + (size_t)e*65536;       bias = bo + (size_t)e*256;       scale = 1.0f; dst = pWo + (size_t)e*69632; }
      if (slice < 16) {
        #pragma unroll
        for (int i = 0; i < 8; ++i) {
          int k = slice*16 + s0 + i;
          o[i] = f2bf(scale * src[(size_t)k*256 + j]);
        }
      } else {
        #pragma unroll
        for (int i = 0; i < 8; ++i) o[i] = 0;
        if (s0 == 0) {
          float a = scale * bias[j];
          unsigned short h = f2bf(a);
          o[0] = h; o[1] = f2bf(a - bf2f(h));
        }
      }
      dp = dst + (size_t)slice*4096 + jb*512 + l*8;
    } else if (b < 552) {
      int e = b - 544;
      const float* w0 = W0 + (size_t)e*768;
      const float* bb = b0 + (size_t)e*256;
      #pragma unroll
      for (int i = 0; i < 8; ++i) {
        int s = s0 + i;
        unsigned short v = 0;
        if (s < 3) v = f2bf(SREV * w0[(size_t)s*256 + j]);
        else if (s < 6) { float a = SREV * w0[(size_t)(s-3)*256 + j]; unsigned short h = f2bf(a); v = f2bf(a - bf2f(h)); }
        else if (s < 9) v = f2bf(SREV * w0[(size_t)(s-6)*256 + j]);
        else if (s == 9)  v = f2bf(SREV * bb[j]);
        else if (s == 10) { float a = SREV * bb[j]; unsigned short h = f2bf(a); v = f2bf(a - bf2f(h)); }
        o[i] = v;
      }
      dp = pW0 + (size_t)e*4096 + jb*512 + l*8;
    } else {
      int slice = b - 552;
      if (slice < 16) {
        #pragma unroll
        for (int i = 0; i < 8; ++i) {
          int k = slice*16 + s0 + i;
          o[i] = f2bf(Wd1[(size_t)k*256 + j]);
        }
      } else {
        #pragma unroll
        for (int i = 0; i < 8; ++i) o[i] = 0;
        if (s0 == 0) {
          float a = bd1[j];
          unsigned short h = f2bf(a);
          o[0] = h; o[1] = f2bf(a - bf2f(h));
        }
      }
      dp = pWd1 + (size_t)slice*4096 + jb*512 + l*8;
    }
    uint4 v;
    v.x = (uint32_t)o[0] | ((uint32_t)o[1] << 16);
    v.y = (uint32_t)o[2] | ((uint32_t)o[3] << 16);
    v.z = (uint32_t)o[4] | ((uint32_t)o[5] << 16);
    v.w = (uint32_t)o[6] | ((uint32_t)o[7] << 16);
    *(uint4*)dp = v;
    return;
  }

  // ---------------- router (f32 + f64 fallback) ----------------
  int rb = b - 569;
  for (int i = tid; i < RH; i += 512) {
    w1f[i*4+0] = Wr1[i];
    w1f[i*4+1] = Wr1[352 + i];
    w1f[i*4+2] = Wr1[704 + i];
    w1f[i*4+3] = br1[i];
  }
  for (int i = tid; i < RH*8; i += 512) w2f[i] = Wr2[i];
  if (tid < 8) lcnt[tid] = 0;
  __syncthreads();

  int n = rb*512 + tid;
  float c0 = ctx[(size_t)n*3+0];
  float c1 = ctx[(size_t)n*3+1];
  float c2 = ctx[(size_t)n*3+2];
  float lg[8];
  #pragma unroll
  for (int e = 0; e < 8; ++e) lg[e] = br2[e];
  for (int j = 0; j < RH; ++j) {
    const float* a = &w1f[j*4];
    float h = fmaf(c0, a[0], fmaf(c1, a[1], fmaf(c2, a[2], a[3])));
    h = h > 0.0f ? h : 0.0f;
    const float* bq = &w2f[j*8];
    lg[0] = fmaf(h, bq[0], lg[0]); lg[1] = fmaf(h, bq[1], lg[1]);
    lg[2] = fmaf(h, bq[2], lg[2]); lg[3] = fmaf(h, bq[3], lg[3]);
    lg[4] = fmaf(h, bq[4], lg[4]); lg[5] = fmaf(h, bq[5], lg[5]);
    lg[6] = fmaf(h, bq[6], lg[6]); lg[7] = fmaf(h, bq[7], lg[7]);
  }
  // top-3 (need v2 for the ambiguity guard)
  float v0 = -1e30f, v1 = -1e30f, v2 = -1e30f; int i0 = 0, i1 = 0;
  #pragma unroll
  for (int e = 0; e < 8; ++e) {
    float lv = lg[e];
    if (lv > v0)      { v2 = v1; v1 = v0; i1 = i0; v0 = lv; i0 = e; }
    else if (lv > v1) { v2 = v1; v1 = lv; i1 = e; }
    else if (lv > v2) { v2 = lv; }
  }
  float d10 = v1 - v0;   // <= 0
  if (v1 - v2 < 1e-3f) {
    // ambiguous top-2 boundary: exact f64 recompute (rare, exec-masked)
    double dg[8];
    #pragma unroll
    for (int e = 0; e < 8; ++e) dg[e] = (double)br2[e];
    for (int j = 0; j < RH; ++j) {
      double h = (double)c0*(double)Wr1[j] + (double)c1*(double)Wr1[352+j]
               + (double)c2*(double)Wr1[704+j] + (double)br1[j];
      h = h > 0.0 ? h : 0.0;
      #pragma unroll
      for (int e = 0; e < 8; ++e) dg[e] += h * (double)Wr2[j*8+e];
    }
    double dv0 = -1e300, dv1 = -1e300; int di0 = 0, di1 = 0;
    #pragma unroll
    for (int e = 0; e < 8; ++e) {
      double lv = dg[e];
      if (lv > dv0)      { dv1 = dv0; di1 = di0; dv0 = lv; di0 = e; }
      else if (lv > dv1) { dv1 = lv; di1 = e; }
    }
    i0 = di0; i1 = di1; d10 = (float)(dv1 - dv0);
  }
  float ex = __expf(d10);
  float s = 1.0f / (1.0f + ex);
  uint4 t;
  t.x = (uint32_t)i0 | ((uint32_t)i1 << 8);
  t.y = __builtin_bit_cast(uint32_t, s);
  t.z = __builtin_bit_cast(uint32_t, ex * s);
  t.w = 0;
  topk[n] = t;
  atomicAdd(&lcnt[i0], 1u); atomicAdd(&lcnt[i1], 1u);
  __syncthreads();
  if (tid < 8) atomicAdd(&counts[tid], lcnt[tid]);
}

// ---------------- K3: scatter (local prefix-sum, hierarchical atomics) --------
__global__ __launch_bounds__(256) void scatter_kernel(
    const uint4* __restrict__ topk, const uint32_t* __restrict__ counts,
    uint32_t* __restrict__ cursors, uint32_t* __restrict__ plist,
    float* __restrict__ pw)
{
  __shared__ uint32_t lc[8], lb[8], offs[8];
  int tid = threadIdx.x;
  if (tid < 8) {
    lc[tid] = 0;
    uint32_t o = 0;
    for (int k = 0; k < tid; ++k) o += counts[k];
    offs[tid] = o;
  }
  __syncthreads();
  int n = blockIdx.x*256 + tid;
  uint4 t = topk[n];
  uint32_t e0 = t.x & 255u, e1 = (t.x >> 8) & 255u;
  uint32_t p0 = atomicAdd(&lc[e0], 1u);
  uint32_t p1 = atomicAdd(&lc[e1], 1u);
  __syncthreads();
  if (tid < 8) lb[tid] = offs[tid] + atomicAdd(&cursors[tid], lc[tid]);
  __syncthreads();
  uint32_t d0 = lb[e0] + p0, d1 = lb[e1] + p1;
  plist[d0] = ((uint32_t)n << 1);      pw[d0] = __builtin_bit_cast(float, t.y);
  plist[d1] = ((uint32_t)n << 1) | 1u; pw[d1] = __builtin_bit_cast(float, t.z);
}

// ---------------- K4: fused SIREN expert kernel (R6 structure) ----------------
// ONE TILE PER BLOCK (ordered dispatch => L2-resident weights). 256 thr /
// 4 waves (j-quarters), BME=64, 3 blocks/CU. A-weights stream through a
// 5-slot register window via opaque asm global_load_dwordx4 + counted vmcnt.
// K-loop: asm-load + vwait + 2x ds_read_b128 + 4x MFMA, no barriers.
// Copy-out restored to the Round-6 interleaved form (183-us binary).
// LDS (static 34KB): hB 32KB (64 rows x 512B, xor-swizzled) + xB 2KB.
__global__ __launch_bounds__(256, 3) void expert_kernel(
    const float* __restrict__ x, const uint32_t* __restrict__ counts,
    const uint32_t* __restrict__ plist, const float* __restrict__ pw,
    const short* __restrict__ pW0, const short* __restrict__ pWh,
    const short* __restrict__ pWo, short* __restrict__ outbuf)
{
  __shared__ __align__(16) uint8_t smem[34816];
  uint8_t* hB = smem;           // 32768
  uint8_t* xB = smem + 32768;   // 2048

  int tid = threadIdx.x;
  int lane = tid & 63;
  int jq = tid >> 6;            // 4 waves: j-quarter (64 features each)
  int aoff = jq*2048 + lane*16; // byte offset of frag0 within a slice

  bf16x8 bbias;
  #pragma unroll
  for (int i = 0; i < 8; ++i) bbias[i] = 0;
  if (lane < 32) { bbias[0] = (short)0x3F80; bbias[1] = (short)0x3F80; }

  bf16x8 aw[5][2];
  f32x16 acc[2][2];

  int rr = tid >> 2;            // copy-out row (0..63), 4 threads per row
  int rq = tid & 3;

  // resolve (expert, tile) + local prefix-sum of counts
  uint32_t tt = blockIdx.x;
  int e = -1; uint32_t cnt = 0, off = 0;
  #pragma unroll 1
  for (int ee = 0; ee < 8; ++ee) {
    uint32_t c = counts[ee];
    uint32_t nt = (c + 63u) >> 6;
    if (tt < nt) { e = ee; cnt = c; break; }
    tt -= nt; off += c;
  }
  if (e < 0) return;
  uint32_t base = off + (tt << 6);
  int nvalid = (int)cnt - (int)(tt << 6); if (nvalid > 64) nvalid = 64;

  uint64_t matp[4];
  matp[0] = (uint64_t)(uintptr_t)(pWh + (size_t)(e*3+0)*69632);
  matp[1] = (uint64_t)(uintptr_t)(pWh + (size_t)(e*3+1)*69632);
  matp[2] = (uint64_t)(uintptr_t)(pWh + (size_t)(e*3+2)*69632);
  matp[3] = (uint64_t)(uintptr_t)(pWo + (size_t)e*69632);

  // prologue: issue slices 0..3 of layer-1 weights (land during L0 phase)
  {
    uint64_t pb = matp[0] + (uint64_t)aoff;
    AWLOAD(aw[0][0], aw[0][1], pb);
    AWLOAD(aw[1][0], aw[1][1], pb + 8192);
    AWLOAD(aw[2][0], aw[2][1], pb + 16384);
    AWLOAD(aw[3][0], aw[3][1], pb + 24576);
  }

  // per-point metadata
  float wgt[2];
  #pragma unroll
  for (int c = 0; c < 2; ++c) {
    int n = c*32 + (lane & 31);
    wgt[c] = (n < nvalid) ? pw[base + n] : 0.0f;
  }
  uint32_t psv = (rr < nvalid) ? plist[base + rr] : 0u;

  // stage layer-0 B tile (x hi/lo + ones) in xB
  if (tid < 64) {
    float x0 = 0.0f, x1 = 0.0f, x2 = 0.0f;
    if (tid < nvalid) {
      uint32_t v = plist[base + tid];
      const float* xp = x + (size_t)(v >> 1)*3;
      x0 = xp[0]; x1 = xp[1]; x2 = xp[2];
    }
    unsigned short h0 = f2bf(x0), h1 = f2bf(x1), h2 = f2bf(x2);
    unsigned short l0 = f2bf(x0 - bf2f(h0)), l1 = f2bf(x1 - bf2f(h1)), l2 = f2bf(x2 - bf2f(h2));
    uint4 r0, r1;
    r0.x = (uint32_t)h0 | ((uint32_t)h1 << 16);
    r0.y = (uint32_t)h2 | ((uint32_t)h0 << 16);
    r0.z = (uint32_t)h1 | ((uint32_t)h2 << 16);
    r0.w = (uint32_t)l0 | ((uint32_t)l1 << 16);
    r1.x = (uint32_t)l2 | (0x3F80u << 16);
    r1.y = 0x3F80u;
    r1.z = 0u; r1.w = 0u;
    uint4* dst = (uint4*)(xB + tid*32);
    dst[0] = r0; dst[1] = r1;
  }

  // layer-0 A fragments (normal loads; one-time per tile)
  const uint8_t* pw0e = (const uint8_t*)(pW0 + (size_t)e*4096);
  bf16x8 a0[2];
  a0[0] = *(const bf16x8*)(pw0e + aoff);
  a0[1] = *(const bf16x8*)(pw0e + aoff + 1024);

  __syncthreads();            // xB ready

  #pragma unroll
  for (int a2 = 0; a2 < 2; ++a2)
    #pragma unroll
    for (int c = 0; c < 2; ++c)
      #pragma unroll
      for (int r = 0; r < 16; ++r) acc[a2][c][r] = 0.0f;

  // layer 0: single K=16 step
  {
    bf16x8 bv[2];
    #pragma unroll
    for (int c = 0; c < 2; ++c) {
      int n = c*32 + (lane & 31);
      bv[c] = *(const bf16x8*)(xB + n*32 + ((lane >> 5)*16));
    }
    #pragma unroll
    for (int a2 = 0; a2 < 2; ++a2)
      #pragma unroll
      for (int c = 0; c < 2; ++c)
        acc[a2][c] = mfma_bf16(a0[a2], bv[c], acc[a2][c]);
  }

#define WRITE_SIN() { _Pragma("unroll") \
    for (int a2 = 0; a2 < 2; ++a2) { \
      int jb = jq*2 + a2; \
      _Pragma("unroll") \
      for (int c = 0; c < 2; ++c) { \
        int n = c*32 + (lane & 31); \
        uint32_t rowb = (uint32_t)n * 512u; \
        uint32_t sw = (uint32_t)((n & 7) << 4); \
        _Pragma("unroll") \
        for (int g = 0; g < 4; ++g) { \
          float s0f = vsin1(acc[a2][c][g*4+0]); \
          float s1f = vsin1(acc[a2][c][g*4+1]); \
          float s2f = vsin1(acc[a2][c][g*4+2]); \
          float s3f = vsin1(acc[a2][c][g*4+3]); \
          uint2 pv; \
          pv.x = (uint32_t)f2bf(s0f) | ((uint32_t)f2bf(s1f) << 16); \
          pv.y = (uint32_t)f2bf(s2f) | ((uint32_t)f2bf(s3f) << 16); \
          int j0 = jb*32 + g*8 + ((lane >> 5) << 2); \
          uint32_t off2 = (rowb + (uint32_t)(j0*2)) ^ sw; \
          *(uint2*)(hB + off2) = pv; \
        } \
      } \
    } }

  WRITE_SIN();                // h0 -> hB
  __syncthreads();            // h0 visible

  // one K-step: global step u = L*17+kb; slice slot u%5; prefetch u+4.
#define STEP(L, kb) { \
    enum { u_ = (L)*17 + (kb), ps_ = u_ + 4, us_ = u_ % 5, pss_ = ps_ % 5 }; \
    if (ps_ <= 67) { \
      uint64_t pa_ = matp[ps_/17] + (uint64_t)((ps_%17)*8192) + (uint64_t)aoff; \
      AWLOAD(aw[pss_][0], aw[pss_][1], pa_); \
    } \
    if (u_ <= 63)      { VWAIT(8, aw[us_][0], aw[us_][1]); } \
    else if (u_ == 64) { VWAIT(6, aw[us_][0], aw[us_][1]); } \
    else if (u_ == 65) { VWAIT(4, aw[us_][0], aw[us_][1]); } \
    else if (u_ == 66) { VWAIT(2, aw[us_][0], aw[us_][1]); } \
    else               { VWAIT(0, aw[us_][0], aw[us_][1]); } \
    bf16x8 bv0_, bv1_; \
    if ((kb) < 16) { \
      { int n_ = (lane & 31); \
        uint32_t off_ = ((uint32_t)n_*512u + (uint32_t)((kb)*32) + (uint32_t)((lane >> 5)*16)) \
                        ^ (uint32_t)((n_ & 7) << 4); \
        bv0_ = *(const bf16x8*)(hB + off_); } \
      { int n_ = 32 + (lane & 31); \
        uint32_t off_ = ((uint32_t)n_*512u + (uint32_t)((kb)*32) + (uint32_t)((lane >> 5)*16)) \
                        ^ (uint32_t)((n_ & 7) << 4); \
        bv1_ = *(const bf16x8*)(hB + off_); } \
    } else { bv0_ = bbias; bv1_ = bbias; } \
    acc[0][0] = mfma_bf16(aw[us_][0], bv0_, acc[0][0]); \
    acc[1][0] = mfma_bf16(aw[us_][1], bv0_, acc[1][0]); \
    acc[0][1] = mfma_bf16(aw[us_][0], bv1_, acc[0][1]); \
    acc[1][1] = mfma_bf16(aw[us_][1], bv1_, acc[1][1]); \
}
#define LAYER17(L) STEP(L,0) STEP(L,1) STEP(L,2) STEP(L,3) STEP(L,4) STEP(L,5) \
    STEP(L,6) STEP(L,7) STEP(L,8) STEP(L,9) STEP(L,10) STEP(L,11) STEP(L,12) \
    STEP(L,13) STEP(L,14) STEP(L,15) STEP(L,16)

#define ZACC() { _Pragma("unroll") for (int a2 = 0; a2 < 2; ++a2) \
    _Pragma("unroll") for (int c = 0; c < 2; ++c) \
    _Pragma("unroll") for (int r = 0; r < 16; ++r) acc[a2][c][r] = 0.0f; }

  ZACC(); LAYER17(0)
  __syncthreads(); WRITE_SIN(); __syncthreads();
  ZACC(); LAYER17(1)
  __syncthreads(); WRITE_SIN(); __syncthreads();
  ZACC(); LAYER17(2)
  __syncthreads(); WRITE_SIN(); __syncthreads();
  ZACC(); LAYER17(3)
  __syncthreads();
  // output layer: gate-weight, stage to hB
  #pragma unroll
  for (int a2 = 0; a2 < 2; ++a2) {
    int jb = jq*2 + a2;
    #pragma unroll
    for (int c = 0; c < 2; ++c) {
      int n = c*32 + (lane & 31);
      float w = wgt[c];
      uint32_t rowb = (uint32_t)n * 512u;
      uint32_t sw = (uint32_t)((n & 7) << 4);
      #pragma unroll
      for (int g = 0; g < 4; ++g) {
        float s0f = acc[a2][c][g*4+0] * w;
        float s1f = acc[a2][c][g*4+1] * w;
        float s2f = acc[a2][c][g*4+2] * w;
        float s3f = acc[a2][c][g*4+3] * w;
        uint2 pv;
        pv.x = (uint32_t)f2bf(s0f) | ((uint32_t)f2bf(s1f) << 16);
        pv.y = (uint32_t)f2bf(s2f) | ((uint32_t)f2bf(s3f) << 16);
        int j0 = jb*32 + g*8 + ((lane >> 5) << 2);
        uint32_t off2 = (rowb + (uint32_t)(j0*2)) ^ sw;
        *(uint2*)(hB + off2) = pv;
      }
    }
  }
  __syncthreads();
  // copy out (Round-6 interleaved form: 16B chunk index c*4+rq per row)
  if (rr < nvalid) {
    uint4* dst = (uint4*)(outbuf + ((size_t)(psv & 1)*N_PTS + (size_t)(psv >> 1))*256);
    uint32_t rowb = (uint32_t)rr*512u;
    uint32_t sw = (uint32_t)((rr & 7) << 4);
    #pragma unroll
    for (int c = 0; c < 8; ++c) {
      int ch = c*4 + rq;
      dst[ch] = *(const uint4*)(hB + ((rowb + (uint32_t)(ch*16)) ^ sw));
    }
  }
}

// ---------------- K5: decoder (R6-template: asm weight window, no K-barriers) --
// 2048 blocks x 256 thr (64 pts/block), 3 blocks/CU. Sum slots -> hB (bf16),
// 17-step K-loop with Wd1 in 5-slot asm window, relu+dot(Wd2)+reduce.
__global__ __launch_bounds__(256, 3) void decoder_kernel(
    const short* __restrict__ outbuf, const short* __restrict__ pWd1,
    const float* __restrict__ Wd2v, const float* __restrict__ bd2,
    float* __restrict__ outp)
{
  __shared__ __align__(16) uint8_t smem[34816];
  uint8_t* hB = smem;                       // 32768
  float* wd2  = (float*)(smem + 32768);     // 1024
  float* part = (float*)(smem + 33792);     // [4][64] = 1024

  int tid = threadIdx.x;
  int lane = tid & 63;
  int jq = tid >> 6;
  int aoff = jq*2048 + lane*16;
  int tbase = blockIdx.x * 64;
  int rr = tid >> 2;
  int rq = tid & 3;

  bf16x8 bbias;
  #pragma unroll
  for (int i = 0; i < 8; ++i) bbias[i] = 0;
  if (lane < 32) { bbias[0] = (short)0x3F80; bbias[1] = (short)0x3F80; }

  bf16x8 aw[5][2];
  f32x16 acc[2][2];

  uint64_t wp = (uint64_t)(uintptr_t)pWd1;
  // prologue: slices 0..3
  {
    uint64_t pb = wp + (uint64_t)aoff;
    AWLOAD(aw[0][0], aw[0][1], pb);
    AWLOAD(aw[1][0], aw[1][1], pb + 8192);
    AWLOAD(aw[2][0], aw[2][1], pb + 16384);
    AWLOAD(aw[3][0], aw[3][1], pb + 24576);
  }

  wd2[tid] = Wd2v[tid];

  // stage: sum the two slots -> hB (bf16, xor-swizzled rows)
  {
    const short* o0 = outbuf + (size_t)(tbase + rr)*256 + rq*64;
    const short* o1 = o0 + (size_t)N_PTS*256;
    uint32_t rowb = (uint32_t)rr*512u + (uint32_t)rq*128u;
    uint32_t sw = (uint32_t)((rr & 7) << 4);
    #pragma unroll
    for (int c = 0; c < 8; ++c) {
      uint4 a  = *(const uint4*)(o0 + c*8);
      uint4 bq = *(const uint4*)(o1 + c*8);
      uint4 ov;
      uint32_t* ap = (uint32_t*)&a;
      uint32_t* bp = (uint32_t*)&bq;
      uint32_t* op = (uint32_t*)&ov;
      #pragma unroll
      for (int w = 0; w < 4; ++w) {
        uint32_t ua = ap[w], ub = bp[w];
        float f0 = bf2f((unsigned short)(ua & 0xFFFFu)) + bf2f((unsigned short)(ub & 0xFFFFu));
        float f1 = bf2f((unsigned short)(ua >> 16))     + bf2f((unsigned short)(ub >> 16));
        op[w] = (uint32_t)f2bf(f0) | ((uint32_t)f2bf(f1) << 16);
      }
      *(uint4*)(hB + ((rowb + (uint32_t)(c*16)) ^ sw)) = ov;
    }
  }
  __syncthreads();

  #pragma unroll
  for (int a2 = 0; a2 < 2; ++a2)
    #pragma unroll
    for (int c = 0; c < 2; ++c)
      #pragma unroll
      for (int r = 0; r < 16; ++r) acc[a2][c][r] = 0.0f;

#define DSTEP(kb) { \
    enum { ps_ = (kb) + 4, us_ = (kb) % 5, pss_ = ps_ % 5 }; \
    if (ps_ <= 16) { \
      uint64_t pa_ = wp + (uint64_t)(ps_*8192) + (uint64_t)aoff; \
      AWLOAD(aw[pss_][0], aw[pss_][1], pa_); \
    } \
    if ((kb) <= 12)      { VWAIT(8, aw[us_][0], aw[us_][1]); } \
    else if ((kb) == 13) { VWAIT(6, aw[us_][0], aw[us_][1]); } \
    else if ((kb) == 14) { VWAIT(4, aw[us_][0], aw[us_][1]); } \
    else if ((kb) == 15) { VWAIT(2, aw[us_][0], aw[us_][1]); } \
    else                 { VWAIT(0, aw[us_][0], aw[us_][1]); } \
    bf16x8 bv0_, bv1_; \
    if ((kb) < 16) { \
      { int n_ = (lane & 31); \
        uint32_t off_ = ((uint32_t)n_*512u + (uint32_t)((kb)*32) + (uint32_t)((lane >> 5)*16)) \
                        ^ (uint32_t)((n_ & 7) << 4); \
        bv0_ = *(const bf16x8*)(hB + off_); } \
      { int n_ = 32 + (lane & 31); \
        uint32_t off_ = ((uint32_t)n_*512u + (uint32_t)((kb)*32) + (uint32_t)((lane >> 5)*16)) \
                        ^ (uint32_t)((n_ & 7) << 4); \
        bv1_ = *(const bf16x8*)(hB + off_); } \
    } else { bv0_ = bbias; bv1_ = bbias; } \
    acc[0][0] = mfma_bf16(aw[us_][0], bv0_, acc[0][0]); \
    acc[1][0] = mfma_bf16(aw[us_][1], bv0_, acc[1][0]); \
    acc[0][1] = mfma_bf16(aw[us_][0], bv1_, acc[0][1]); \
    acc[1][1] = mfma_bf16(aw[us_][1], bv1_, acc[1][1]); \
}
  DSTEP(0)  DSTEP(1)  DSTEP(2)  DSTEP(3)  DSTEP(4)  DSTEP(5)
  DSTEP(6)  DSTEP(7)  DSTEP(8)  DSTEP(9)  DSTEP(10) DSTEP(11)
  DSTEP(12) DSTEP(13) DSTEP(14) DSTEP(15) DSTEP(16)

  // epilogue: relu, dot with Wd2, reduce
  float p0 = 0.0f, p1 = 0.0f;
  #pragma unroll
  for (int a2 = 0; a2 < 2; ++a2) {
    int jb = jq*2 + a2;
    #pragma unroll
    for (int c = 0; c < 2; ++c) {
      #pragma unroll
      for (int r = 0; r < 16; ++r) {
        int j = jb*32 + (r & 3) + ((r >> 2) << 3) + ((lane >> 5) << 2);
        float v = acc[a2][c][r];
        v = v > 0.0f ? v : 0.0f;
        float t = v * wd2[j];
        if (c == 0) p0 += t; else p1 += t;
      }
    }
  }
  p0 += __shfl_xor(p0, 32);
  p1 += __shfl_xor(p1, 32);
  if (lane < 32) {
    part[jq*64 + lane] = p0;
    part[jq*64 + 32 + lane] = p1;
  }
  __syncthreads();
  if (tid < 64)
    outp[tbase + tid] = part[tid] + part[64 + tid] + part[128 + tid]
                      + part[192 + tid] + bd2[0];
}

// ---------------- host ----------------
extern "C" void kernel_launch(void* const* d_in, const int* in_sizes, int n_in,
                              void* d_out, int out_size, void* d_ws, size_t ws_size,
                              hipStream_t stream) {
  const float* x   = (const float*)d_in[0];
  const float* ctx = (const float*)d_in[1];
  const float* Wr1 = (const float*)d_in[2];
  const float* br1 = (const float*)d_in[3];
  const float* Wr2 = (const float*)d_in[4];
  const float* br2 = (const float*)d_in[5];
  const float* W0  = (const float*)d_in[6];
  const float* b0  = (const float*)d_in[7];
  const float* Wh  = (const float*)d_in[8];
  const float* bh  = (const float*)d_in[9];
  const float* Wo  = (const float*)d_in[10];
  const float* bo  = (const float*)d_in[11];
  const float* Wd1 = (const float*)d_in[12];
  const float* bd1 = (const float*)d_in[13];
  const float* Wd2 = (const float*)d_in[14];
  const float* bd2 = (const float*)d_in[15];
  float* out = (float*)d_out;

  const size_t WS_COUNTS  = 0;
  const size_t WS_CURSORS = 32;
  const size_t WS_TOPK    = 1024;
  const size_t WS_PLIST   = WS_TOPK  + (size_t)N_PTS*16;
  const size_t WS_PW      = WS_PLIST + (size_t)N_PTS*8;
  const size_t WS_PW0     = WS_PW    + (size_t)N_PTS*8;
  const size_t WS_PWH     = WS_PW0   + (size_t)8*8192;
  const size_t WS_PWO     = WS_PWH   + (size_t)24*139264;
  const size_t WS_PWD1    = WS_PWO   + (size_t)8*139264;
  const size_t WS_OUT     = WS_PWD1  + (size_t)139264;
  const size_t WS_END     = WS_OUT   + (size_t)2*N_PTS*256*2;

  if (ws_size < WS_END) {
    hipMemsetAsync(d_out, 0xFF, (size_t)out_size*4, stream);
    return;
  }

  uint8_t* ws = (uint8_t*)d_ws;
  uint32_t* counts  = (uint32_t*)(ws + WS_COUNTS);
  uint32_t* cursors = (uint32_t*)(ws + WS_CURSORS);
  uint4*    topk    = (uint4*)   (ws + WS_TOPK);
  uint32_t* plist   = (uint32_t*)(ws + WS_PLIST);
  float*    pw      = (float*)   (ws + WS_PW);
  short*    pW0     = (short*)   (ws + WS_PW0);
  short*    pWh     = (short*)   (ws + WS_PWH);
  short*    pWo     = (short*)   (ws + WS_PWO);
  short*    pWd1    = (short*)   (ws + WS_PWD1);
  short*    outbuf  = (short*)   (ws + WS_OUT);

  hipMemsetAsync(counts, 0, 64, stream);   // counts[8] + cursors[8]

  setup_kernel  <<<825,  512, 0, stream>>>(W0, b0, Wh, bh, Wo, bo, Wd1, bd1,
                                           pW0, pWh, pWo, pWd1,
                                           ctx, Wr1, br1, Wr2, br2, topk, counts);
  scatter_kernel<<<512,  256, 0, stream>>>(topk, counts, cursors, plist, pw);
  expert_kernel <<<4104, 256, 0, stream>>>(x, counts, plist, pw,
                                           pW0, pWh, pWo, outbuf);
  decoder_kernel<<<2048, 256, 0, stream>>>(outbuf, pWd1, Wd2, bd2, out);
}

// Round 13
// 270.933 us; speedup vs baseline: 1.2412x; 1.2412x over previous
//
#include <hip/hip_runtime.h>
#include <stdint.h>

#define N_PTS 131072
#define RH    352
#define SREV  4.774648292756860f   /* 30 / (2*pi) */

typedef short  bf16x8 __attribute__((ext_vector_type(8)));
typedef float  f32x16 __attribute__((ext_vector_type(16)));

// ---------------- helpers ----------------
__device__ __forceinline__ unsigned short f2bf(float f) {
  uint32_t u = __builtin_bit_cast(uint32_t, f);
  u = (u + 0x7FFFu + ((u >> 16) & 1u)) >> 16;
  return (unsigned short)u;
}
__device__ __forceinline__ float bf2f(unsigned short s) {
  return __builtin_bit_cast(float, ((uint32_t)s) << 16);
}
__device__ __forceinline__ float vsin1(float x) {   // sin(2*pi*x)
  float xf = x - floorf(x);
  float r;
  asm("v_sin_f32 %0, %1" : "=v"(r) : "v"(xf));
  return r;
}
__device__ __forceinline__ f32x16 mfma_bf16(bf16x8 a, bf16x8 b, f32x16 c) {
  return __builtin_amdgcn_mfma_f32_32x32x16_bf16(a, b, c, 0, 0, 0);
}

// opaque async weight load: compiler cannot sink or track it
#define AWLOAD(d0, d1, addr64) \
  asm volatile("global_load_dwordx4 %0, %2, off\n\t" \
               "global_load_dwordx4 %1, %2, off offset:1024" \
               : "=&v"(d0), "=&v"(d1) : "v"(addr64))

// counted wait; register ties order the dependent MFMAs without sched_barrier
#define VWAIT(N, r0, r1) \
  asm volatile("s_waitcnt vmcnt(" #N ")" : "+v"(r0), "+v"(r1))

// ---------------- K0: fused pack (blocks 0..568) + router (blocks 569..824) ----
// pack: weights -> bf16 MFMA A-fragment layout.
// A-frag (32x32x16): lane l holds A[j = jb*32+(l&31)][k = kb*16 + (l>>5)*8 + i].
// Slice kb = 8 jb * 1KB contiguous. Slice 16 = bias hi/lo (k-slots 0,1) with B=1.
// router: all-f64 LDS-staged logits -> exact top-2 (proven; f32 fast-path
// reverted: clustered logits made the any-lane fallback fire in ~73% of waves).
__global__ __launch_bounds__(512) void setup_kernel(
    const float* __restrict__ W0, const float* __restrict__ b0,
    const float* __restrict__ Wh, const float* __restrict__ bh,
    const float* __restrict__ Wo, const float* __restrict__ bo,
    const float* __restrict__ Wd1, const float* __restrict__ bd1,
    short* __restrict__ pW0, short* __restrict__ pWh,
    short* __restrict__ pWo, short* __restrict__ pWd1,
    const float* __restrict__ ctx, const float* __restrict__ Wr1,
    const float* __restrict__ br1, const float* __restrict__ Wr2,
    const float* __restrict__ br2, uint4* __restrict__ topk,
    uint32_t* __restrict__ counts)
{
  __shared__ double w1d[RH*4];
  __shared__ double w2d[RH*8];
  __shared__ uint32_t lcnt[8];
  int b = blockIdx.x, tid = threadIdx.x;

  if (b < 569) {                        // ---------------- pack ----------------
    int jb = tid >> 6, l = tid & 63;
    int j  = jb*32 + (l & 31);
    int s0 = (l >> 5) * 8;
    unsigned short o[8];
    short* dp;
    if (b < 544) {
      int m = b / 17, slice = b % 17;
      int e = m >> 2, t = m & 3;
      const float* src; const float* bias; float scale; short* dst;
      if (t < 3) { src = Wh + (size_t)(e*3+t)*65536; bias = bh + (size_t)(e*3+t)*256; scale = SREV; dst = pWh + (size_t)(e*3+t)*69632; }
      else       { src = Wo + (size_t)e*65536;       bias = bo + (size_t)e*256;       scale = 1.0f; dst = pWo + (size_t)e*69632; }
      if (slice < 16) {
        #pragma unroll
        for (int i = 0; i < 8; ++i) {
          int k = slice*16 + s0 + i;
          o[i] = f2bf(scale * src[(size_t)k*256 + j]);
        }
      } else {
        #pragma unroll
        for (int i = 0; i < 8; ++i) o[i] = 0;
        if (s0 == 0) {
          float a = scale * bias[j];
          unsigned short h = f2bf(a);
          o[0] = h; o[1] = f2bf(a - bf2f(h));
        }
      }
      dp = dst + (size_t)slice*4096 + jb*512 + l*8;
    } else if (b < 552) {
      int e = b - 544;
      const float* w0 = W0 + (size_t)e*768;
      const float* bb = b0 + (size_t)e*256;
      #pragma unroll
      for (int i = 0; i < 8; ++i) {
        int s = s0 + i;
        unsigned short v = 0;
        if (s < 3) v = f2bf(SREV * w0[(size_t)s*256 + j]);
        else if (s < 6) { float a = SREV * w0[(size_t)(s-3)*256 + j]; unsigned short h = f2bf(a); v = f2bf(a - bf2f(h)); }
        else if (s < 9) v = f2bf(SREV * w0[(size_t)(s-6)*256 + j]);
        else if (s == 9)  v = f2bf(SREV * bb[j]);
        else if (s == 10) { float a = SREV * bb[j]; unsigned short h = f2bf(a); v = f2bf(a - bf2f(h)); }
        o[i] = v;
      }
      dp = pW0 + (size_t)e*4096 + jb*512 + l*8;
    } else {
      int slice = b - 552;
      if (slice < 16) {
        #pragma unroll
        for (int i = 0; i < 8; ++i) {
          int k = slice*16 + s0 + i;
          o[i] = f2bf(Wd1[(size_t)k*256 + j]);
        }
      } else {
        #pragma unroll
        for (int i = 0; i < 8; ++i) o[i] = 0;
        if (s0 == 0) {
          float a = bd1[j];
          unsigned short h = f2bf(a);
          o[0] = h; o[1] = f2bf(a - bf2f(h));
        }
      }
      dp = pWd1 + (size_t)slice*4096 + jb*512 + l*8;
    }
    uint4 v;
    v.x = (uint32_t)o[0] | ((uint32_t)o[1] << 16);
    v.y = (uint32_t)o[2] | ((uint32_t)o[3] << 16);
    v.z = (uint32_t)o[4] | ((uint32_t)o[5] << 16);
    v.w = (uint32_t)o[6] | ((uint32_t)o[7] << 16);
    *(uint4*)dp = v;
    return;
  }

  // ---------------- router (all-f64, LDS-staged) ----------------
  int rb = b - 569;
  for (int i = tid; i < RH; i += 512) {
    w1d[i*4+0] = (double)Wr1[i];
    w1d[i*4+1] = (double)Wr1[352 + i];
    w1d[i*4+2] = (double)Wr1[704 + i];
    w1d[i*4+3] = (double)br1[i];
  }
  for (int i = tid; i < RH*8; i += 512) w2d[i] = (double)Wr2[i];
  if (tid < 8) lcnt[tid] = 0;
  __syncthreads();

  int n = rb*512 + tid;
  double c0 = (double)ctx[(size_t)n*3+0];
  double c1 = (double)ctx[(size_t)n*3+1];
  double c2 = (double)ctx[(size_t)n*3+2];
  double lg[8];
  #pragma unroll
  for (int e = 0; e < 8; ++e) lg[e] = (double)br2[e];
  for (int j = 0; j < RH; ++j) {
    const double* a = &w1d[j*4];
    double h = c0*a[0] + c1*a[1] + c2*a[2] + a[3];
    h = h > 0.0 ? h : 0.0;
    const double* bq = &w2d[j*8];
    lg[0] += h*bq[0]; lg[1] += h*bq[1]; lg[2] += h*bq[2]; lg[3] += h*bq[3];
    lg[4] += h*bq[4]; lg[5] += h*bq[5]; lg[6] += h*bq[6]; lg[7] += h*bq[7];
  }
  double v0 = -1e300, v1 = -1e300; int i0 = 0, i1 = 0;
  #pragma unroll
  for (int e = 0; e < 8; ++e) {
    double lv = lg[e];
    if (lv > v0)      { v1 = v0; i1 = i0; v0 = lv; i0 = e; }
    else if (lv > v1) { v1 = lv; i1 = e; }
  }
  float ex = __expf((float)(v1 - v0));
  float s = 1.0f / (1.0f + ex);
  uint4 t;
  t.x = (uint32_t)i0 | ((uint32_t)i1 << 8);
  t.y = __builtin_bit_cast(uint32_t, s);
  t.z = __builtin_bit_cast(uint32_t, ex * s);
  t.w = 0;
  topk[n] = t;
  atomicAdd(&lcnt[i0], 1u); atomicAdd(&lcnt[i1], 1u);
  __syncthreads();
  if (tid < 8) atomicAdd(&counts[tid], lcnt[tid]);
}

// ---------------- K3: scatter (local prefix-sum, hierarchical atomics) --------
__global__ __launch_bounds__(256) void scatter_kernel(
    const uint4* __restrict__ topk, const uint32_t* __restrict__ counts,
    uint32_t* __restrict__ cursors, uint32_t* __restrict__ plist,
    float* __restrict__ pw)
{
  __shared__ uint32_t lc[8], lb[8], offs[8];
  int tid = threadIdx.x;
  if (tid < 8) {
    lc[tid] = 0;
    uint32_t o = 0;
    for (int k = 0; k < tid; ++k) o += counts[k];
    offs[tid] = o;
  }
  __syncthreads();
  int n = blockIdx.x*256 + tid;
  uint4 t = topk[n];
  uint32_t e0 = t.x & 255u, e1 = (t.x >> 8) & 255u;
  uint32_t p0 = atomicAdd(&lc[e0], 1u);
  uint32_t p1 = atomicAdd(&lc[e1], 1u);
  __syncthreads();
  if (tid < 8) lb[tid] = offs[tid] + atomicAdd(&cursors[tid], lc[tid]);
  __syncthreads();
  uint32_t d0 = lb[e0] + p0, d1 = lb[e1] + p1;
  plist[d0] = ((uint32_t)n << 1);      pw[d0] = __builtin_bit_cast(float, t.y);
  plist[d1] = ((uint32_t)n << 1) | 1u; pw[d1] = __builtin_bit_cast(float, t.z);
}

// ---------------- K4: fused SIREN expert kernel (R6 structure) ----------------
// ONE TILE PER BLOCK (ordered dispatch => L2-resident weights). 256 thr /
// 4 waves (j-quarters), BME=64, 3 blocks/CU. A-weights stream through a
// 5-slot register window via opaque asm global_load_dwordx4 + counted vmcnt.
// K-loop: asm-load + vwait + 2x ds_read_b128 + 4x MFMA, no barriers.
// Round-6 interleaved copy-out (c*4+rq). RNE f2bf pack throughout.
// LDS (static 34KB): hB 32KB (64 rows x 512B, xor-swizzled) + xB 2KB.
__global__ __launch_bounds__(256, 3) void expert_kernel(
    const float* __restrict__ x, const uint32_t* __restrict__ counts,
    const uint32_t* __restrict__ plist, const float* __restrict__ pw,
    const short* __restrict__ pW0, const short* __restrict__ pWh,
    const short* __restrict__ pWo, short* __restrict__ outbuf)
{
  __shared__ __align__(16) uint8_t smem[34816];
  uint8_t* hB = smem;           // 32768
  uint8_t* xB = smem + 32768;   // 2048

  int tid = threadIdx.x;
  int lane = tid & 63;
  int jq = tid >> 6;            // 4 waves: j-quarter (64 features each)
  int aoff = jq*2048 + lane*16; // byte offset of frag0 within a slice

  bf16x8 bbias;
  #pragma unroll
  for (int i = 0; i < 8; ++i) bbias[i] = 0;
  if (lane < 32) { bbias[0] = (short)0x3F80; bbias[1] = (short)0x3F80; }

  bf16x8 aw[5][2];
  f32x16 acc[2][2];

  int rr = tid >> 2;            // copy-out row (0..63), 4 threads per row
  int rq = tid & 3;

  // resolve (expert, tile) + local prefix-sum of counts
  uint32_t tt = blockIdx.x;
  int e = -1; uint32_t cnt = 0, off = 0;
  #pragma unroll 1
  for (int ee = 0; ee < 8; ++ee) {
    uint32_t c = counts[ee];
    uint32_t nt = (c + 63u) >> 6;
    if (tt < nt) { e = ee; cnt = c; break; }
    tt -= nt; off += c;
  }
  if (e < 0) return;
  uint32_t base = off + (tt << 6);
  int nvalid = (int)cnt - (int)(tt << 6); if (nvalid > 64) nvalid = 64;

  uint64_t matp[4];
  matp[0] = (uint64_t)(uintptr_t)(pWh + (size_t)(e*3+0)*69632);
  matp[1] = (uint64_t)(uintptr_t)(pWh + (size_t)(e*3+1)*69632);
  matp[2] = (uint64_t)(uintptr_t)(pWh + (size_t)(e*3+2)*69632);
  matp[3] = (uint64_t)(uintptr_t)(pWo + (size_t)e*69632);

  // prologue: issue slices 0..3 of layer-1 weights (land during L0 phase)
  {
    uint64_t pb = matp[0] + (uint64_t)aoff;
    AWLOAD(aw[0][0], aw[0][1], pb);
    AWLOAD(aw[1][0], aw[1][1], pb + 8192);
    AWLOAD(aw[2][0], aw[2][1], pb + 16384);
    AWLOAD(aw[3][0], aw[3][1], pb + 24576);
  }

  // per-point metadata
  float wgt[2];
  #pragma unroll
  for (int c = 0; c < 2; ++c) {
    int n = c*32 + (lane & 31);
    wgt[c] = (n < nvalid) ? pw[base + n] : 0.0f;
  }
  uint32_t psv = (rr < nvalid) ? plist[base + rr] : 0u;

  // stage layer-0 B tile (x hi/lo + ones) in xB
  if (tid < 64) {
    float x0 = 0.0f, x1 = 0.0f, x2 = 0.0f;
    if (tid < nvalid) {
      uint32_t v = plist[base + tid];
      const float* xp = x + (size_t)(v >> 1)*3;
      x0 = xp[0]; x1 = xp[1]; x2 = xp[2];
    }
    unsigned short h0 = f2bf(x0), h1 = f2bf(x1), h2 = f2bf(x2);
    unsigned short l0 = f2bf(x0 - bf2f(h0)), l1 = f2bf(x1 - bf2f(h1)), l2 = f2bf(x2 - bf2f(h2));
    uint4 r0, r1;
    r0.x = (uint32_t)h0 | ((uint32_t)h1 << 16);
    r0.y = (uint32_t)h2 | ((uint32_t)h0 << 16);
    r0.z = (uint32_t)h1 | ((uint32_t)h2 << 16);
    r0.w = (uint32_t)l0 | ((uint32_t)l1 << 16);
    r1.x = (uint32_t)l2 | (0x3F80u << 16);
    r1.y = 0x3F80u;
    r1.z = 0u; r1.w = 0u;
    uint4* dst = (uint4*)(xB + tid*32);
    dst[0] = r0; dst[1] = r1;
  }

  // layer-0 A fragments (normal loads; one-time per tile)
  const uint8_t* pw0e = (const uint8_t*)(pW0 + (size_t)e*4096);
  bf16x8 a0[2];
  a0[0] = *(const bf16x8*)(pw0e + aoff);
  a0[1] = *(const bf16x8*)(pw0e + aoff + 1024);

  __syncthreads();            // xB ready

  #pragma unroll
  for (int a2 = 0; a2 < 2; ++a2)
    #pragma unroll
    for (int c = 0; c < 2; ++c)
      #pragma unroll
      for (int r = 0; r < 16; ++r) acc[a2][c][r] = 0.0f;

  // layer 0: single K=16 step
  {
    bf16x8 bv[2];
    #pragma unroll
    for (int c = 0; c < 2; ++c) {
      int n = c*32 + (lane & 31);
      bv[c] = *(const bf16x8*)(xB + n*32 + ((lane >> 5)*16));
    }
    #pragma unroll
    for (int a2 = 0; a2 < 2; ++a2)
      #pragma unroll
      for (int c = 0; c < 2; ++c)
        acc[a2][c] = mfma_bf16(a0[a2], bv[c], acc[a2][c]);
  }

#define WRITE_SIN() { _Pragma("unroll") \
    for (int a2 = 0; a2 < 2; ++a2) { \
      int jb = jq*2 + a2; \
      _Pragma("unroll") \
      for (int c = 0; c < 2; ++c) { \
        int n = c*32 + (lane & 31); \
        uint32_t rowb = (uint32_t)n * 512u; \
        uint32_t sw = (uint32_t)((n & 7) << 4); \
        _Pragma("unroll") \
        for (int g = 0; g < 4; ++g) { \
          float s0f = vsin1(acc[a2][c][g*4+0]); \
          float s1f = vsin1(acc[a2][c][g*4+1]); \
          float s2f = vsin1(acc[a2][c][g*4+2]); \
          float s3f = vsin1(acc[a2][c][g*4+3]); \
          uint2 pv; \
          pv.x = (uint32_t)f2bf(s0f) | ((uint32_t)f2bf(s1f) << 16); \
          pv.y = (uint32_t)f2bf(s2f) | ((uint32_t)f2bf(s3f) << 16); \
          int j0 = jb*32 + g*8 + ((lane >> 5) << 2); \
          uint32_t off2 = (rowb + (uint32_t)(j0*2)) ^ sw; \
          *(uint2*)(hB + off2) = pv; \
        } \
      } \
    } }

  WRITE_SIN();                // h0 -> hB
  __syncthreads();            // h0 visible

  // one K-step: global step u = L*17+kb; slice slot u%5; prefetch u+4.
#define STEP(L, kb) { \
    enum { u_ = (L)*17 + (kb), ps_ = u_ + 4, us_ = u_ % 5, pss_ = ps_ % 5 }; \
    if (ps_ <= 67) { \
      uint64_t pa_ = matp[ps_/17] + (uint64_t)((ps_%17)*8192) + (uint64_t)aoff; \
      AWLOAD(aw[pss_][0], aw[pss_][1], pa_); \
    } \
    if (u_ <= 63)      { VWAIT(8, aw[us_][0], aw[us_][1]); } \
    else if (u_ == 64) { VWAIT(6, aw[us_][0], aw[us_][1]); } \
    else if (u_ == 65) { VWAIT(4, aw[us_][0], aw[us_][1]); } \
    else if (u_ == 66) { VWAIT(2, aw[us_][0], aw[us_][1]); } \
    else               { VWAIT(0, aw[us_][0], aw[us_][1]); } \
    bf16x8 bv0_, bv1_; \
    if ((kb) < 16) { \
      { int n_ = (lane & 31); \
        uint32_t off_ = ((uint32_t)n_*512u + (uint32_t)((kb)*32) + (uint32_t)((lane >> 5)*16)) \
                        ^ (uint32_t)((n_ & 7) << 4); \
        bv0_ = *(const bf16x8*)(hB + off_); } \
      { int n_ = 32 + (lane & 31); \
        uint32_t off_ = ((uint32_t)n_*512u + (uint32_t)((kb)*32) + (uint32_t)((lane >> 5)*16)) \
                        ^ (uint32_t)((n_ & 7) << 4); \
        bv1_ = *(const bf16x8*)(hB + off_); } \
    } else { bv0_ = bbias; bv1_ = bbias; } \
    acc[0][0] = mfma_bf16(aw[us_][0], bv0_, acc[0][0]); \
    acc[1][0] = mfma_bf16(aw[us_][1], bv0_, acc[1][0]); \
    acc[0][1] = mfma_bf16(aw[us_][0], bv1_, acc[0][1]); \
    acc[1][1] = mfma_bf16(aw[us_][1], bv1_, acc[1][1]); \
}
#define LAYER17(L) STEP(L,0) STEP(L,1) STEP(L,2) STEP(L,3) STEP(L,4) STEP(L,5) \
    STEP(L,6) STEP(L,7) STEP(L,8) STEP(L,9) STEP(L,10) STEP(L,11) STEP(L,12) \
    STEP(L,13) STEP(L,14) STEP(L,15) STEP(L,16)

#define ZACC() { _Pragma("unroll") for (int a2 = 0; a2 < 2; ++a2) \
    _Pragma("unroll") for (int c = 0; c < 2; ++c) \
    _Pragma("unroll") for (int r = 0; r < 16; ++r) acc[a2][c][r] = 0.0f; }

  ZACC(); LAYER17(0)
  __syncthreads(); WRITE_SIN(); __syncthreads();
  ZACC(); LAYER17(1)
  __syncthreads(); WRITE_SIN(); __syncthreads();
  ZACC(); LAYER17(2)
  __syncthreads(); WRITE_SIN(); __syncthreads();
  ZACC(); LAYER17(3)
  __syncthreads();
  // output layer: gate-weight, stage to hB
  #pragma unroll
  for (int a2 = 0; a2 < 2; ++a2) {
    int jb = jq*2 + a2;
    #pragma unroll
    for (int c = 0; c < 2; ++c) {
      int n = c*32 + (lane & 31);
      float w = wgt[c];
      uint32_t rowb = (uint32_t)n * 512u;
      uint32_t sw = (uint32_t)((n & 7) << 4);
      #pragma unroll
      for (int g = 0; g < 4; ++g) {
        float s0f = acc[a2][c][g*4+0] * w;
        float s1f = acc[a2][c][g*4+1] * w;
        float s2f = acc[a2][c][g*4+2] * w;
        float s3f = acc[a2][c][g*4+3] * w;
        uint2 pv;
        pv.x = (uint32_t)f2bf(s0f) | ((uint32_t)f2bf(s1f) << 16);
        pv.y = (uint32_t)f2bf(s2f) | ((uint32_t)f2bf(s3f) << 16);
        int j0 = jb*32 + g*8 + ((lane >> 5) << 2);
        uint32_t off2 = (rowb + (uint32_t)(j0*2)) ^ sw;
        *(uint2*)(hB + off2) = pv;
      }
    }
  }
  __syncthreads();
  // copy out (Round-6 interleaved form: 16B chunk index c*4+rq per row)
  if (rr < nvalid) {
    uint4* dst = (uint4*)(outbuf + ((size_t)(psv & 1)*N_PTS + (size_t)(psv >> 1))*256);
    uint32_t rowb = (uint32_t)rr*512u;
    uint32_t sw = (uint32_t)((rr & 7) << 4);
    #pragma unroll
    for (int c = 0; c < 8; ++c) {
      int ch = c*4 + rq;
      dst[ch] = *(const uint4*)(hB + ((rowb + (uint32_t)(ch*16)) ^ sw));
    }
  }
}

// ---------------- K5: decoder (R6-template: asm weight window, no K-barriers) --
// 2048 blocks x 256 thr (64 pts/block), 3 blocks/CU. Sum slots -> hB (bf16),
// 17-step K-loop with Wd1 in 5-slot asm window, relu+dot(Wd2)+reduce.
__global__ __launch_bounds__(256, 3) void decoder_kernel(
    const short* __restrict__ outbuf, const short* __restrict__ pWd1,
    const float* __restrict__ Wd2v, const float* __restrict__ bd2,
    float* __restrict__ outp)
{
  __shared__ __align__(16) uint8_t smem[34816];
  uint8_t* hB = smem;                       // 32768
  float* wd2  = (float*)(smem + 32768);     // 1024
  float* part = (float*)(smem + 33792);     // [4][64] = 1024

  int tid = threadIdx.x;
  int lane = tid & 63;
  int jq = tid >> 6;
  int aoff = jq*2048 + lane*16;
  int tbase = blockIdx.x * 64;
  int rr = tid >> 2;
  int rq = tid & 3;

  bf16x8 bbias;
  #pragma unroll
  for (int i = 0; i < 8; ++i) bbias[i] = 0;
  if (lane < 32) { bbias[0] = (short)0x3F80; bbias[1] = (short)0x3F80; }

  bf16x8 aw[5][2];
  f32x16 acc[2][2];

  uint64_t wp = (uint64_t)(uintptr_t)pWd1;
  // prologue: slices 0..3
  {
    uint64_t pb = wp + (uint64_t)aoff;
    AWLOAD(aw[0][0], aw[0][1], pb);
    AWLOAD(aw[1][0], aw[1][1], pb + 8192);
    AWLOAD(aw[2][0], aw[2][1], pb + 16384);
    AWLOAD(aw[3][0], aw[3][1], pb + 24576);
  }

  wd2[tid] = Wd2v[tid];

  // stage: sum the two slots -> hB (bf16, xor-swizzled rows)
  {
    const short* o0 = outbuf + (size_t)(tbase + rr)*256 + rq*64;
    const short* o1 = o0 + (size_t)N_PTS*256;
    uint32_t rowb = (uint32_t)rr*512u + (uint32_t)rq*128u;
    uint32_t sw = (uint32_t)((rr & 7) << 4);
    #pragma unroll
    for (int c = 0; c < 8; ++c) {
      uint4 a  = *(const uint4*)(o0 + c*8);
      uint4 bq = *(const uint4*)(o1 + c*8);
      uint4 ov;
      uint32_t* ap = (uint32_t*)&a;
      uint32_t* bp = (uint32_t*)&bq;
      uint32_t* op = (uint32_t*)&ov;
      #pragma unroll
      for (int w = 0; w < 4; ++w) {
        uint32_t ua = ap[w], ub = bp[w];
        float f0 = bf2f((unsigned short)(ua & 0xFFFFu)) + bf2f((unsigned short)(ub & 0xFFFFu));
        float f1 = bf2f((unsigned short)(ua >> 16))     + bf2f((unsigned short)(ub >> 16));
        op[w] = (uint32_t)f2bf(f0) | ((uint32_t)f2bf(f1) << 16);
      }
      *(uint4*)(hB + ((rowb + (uint32_t)(c*16)) ^ sw)) = ov;
    }
  }
  __syncthreads();

  #pragma unroll
  for (int a2 = 0; a2 < 2; ++a2)
    #pragma unroll
    for (int c = 0; c < 2; ++c)
      #pragma unroll
      for (int r = 0; r < 16; ++r) acc[a2][c][r] = 0.0f;

#define DSTEP(kb) { \
    enum { ps_ = (kb) + 4, us_ = (kb) % 5, pss_ = ps_ % 5 }; \
    if (ps_ <= 16) { \
      uint64_t pa_ = wp + (uint64_t)(ps_*8192) + (uint64_t)aoff; \
      AWLOAD(aw[pss_][0], aw[pss_][1], pa_); \
    } \
    if ((kb) <= 12)      { VWAIT(8, aw[us_][0], aw[us_][1]); } \
    else if ((kb) == 13) { VWAIT(6, aw[us_][0], aw[us_][1]); } \
    else if ((kb) == 14) { VWAIT(4, aw[us_][0], aw[us_][1]); } \
    else if ((kb) == 15) { VWAIT(2, aw[us_][0], aw[us_][1]); } \
    else                 { VWAIT(0, aw[us_][0], aw[us_][1]); } \
    bf16x8 bv0_, bv1_; \
    if ((kb) < 16) { \
      { int n_ = (lane & 31); \
        uint32_t off_ = ((uint32_t)n_*512u + (uint32_t)((kb)*32) + (uint32_t)((lane >> 5)*16)) \
                        ^ (uint32_t)((n_ & 7) << 4); \
        bv0_ = *(const bf16x8*)(hB + off_); } \
      { int n_ = 32 + (lane & 31); \
        uint32_t off_ = ((uint32_t)n_*512u + (uint32_t)((kb)*32) + (uint32_t)((lane >> 5)*16)) \
                        ^ (uint32_t)((n_ & 7) << 4); \
        bv1_ = *(const bf16x8*)(hB + off_); } \
    } else { bv0_ = bbias; bv1_ = bbias; } \
    acc[0][0] = mfma_bf16(aw[us_][0], bv0_, acc[0][0]); \
    acc[1][0] = mfma_bf16(aw[us_][1], bv0_, acc[1][0]); \
    acc[0][1] = mfma_bf16(aw[us_][0], bv1_, acc[0][1]); \
    acc[1][1] = mfma_bf16(aw[us_][1], bv1_, acc[1][1]); \
}
  DSTEP(0)  DSTEP(1)  DSTEP(2)  DSTEP(3)  DSTEP(4)  DSTEP(5)
  DSTEP(6)  DSTEP(7)  DSTEP(8)  DSTEP(9)  DSTEP(10) DSTEP(11)
  DSTEP(12) DSTEP(13) DSTEP(14) DSTEP(15) DSTEP(16)

  // epilogue: relu, dot with Wd2, reduce
  float p0 = 0.0f, p1 = 0.0f;
  #pragma unroll
  for (int a2 = 0; a2 < 2; ++a2) {
    int jb = jq*2 + a2;
    #pragma unroll
    for (int c = 0; c < 2; ++c) {
      #pragma unroll
      for (int r = 0; r < 16; ++r) {
        int j = jb*32 + (r & 3) + ((r >> 2) << 3) + ((lane >> 5) << 2);
        float v = acc[a2][c][r];
        v = v > 0.0f ? v : 0.0f;
        float t = v * wd2[j];
        if (c == 0) p0 += t; else p1 += t;
      }
    }
  }
  p0 += __shfl_xor(p0, 32);
  p1 += __shfl_xor(p1, 32);
  if (lane < 32) {
    part[jq*64 + lane] = p0;
    part[jq*64 + 32 + lane] = p1;
  }
  __syncthreads();
  if (tid < 64)
    outp[tbase + tid] = part[tid] + part[64 + tid] + part[128 + tid]
                      + part[192 + tid] + bd2[0];
}

// ---------------- host ----------------
extern "C" void kernel_launch(void* const* d_in, const int* in_sizes, int n_in,
                              void* d_out, int out_size, void* d_ws, size_t ws_size,
                              hipStream_t stream) {
  const float* x   = (const float*)d_in[0];
  const float* ctx = (const float*)d_in[1];
  const float* Wr1 = (const float*)d_in[2];
  const float* br1 = (const float*)d_in[3];
  const float* Wr2 = (const float*)d_in[4];
  const float* br2 = (const float*)d_in[5];
  const float* W0  = (const float*)d_in[6];
  const float* b0  = (const float*)d_in[7];
  const float* Wh  = (const float*)d_in[8];
  const float* bh  = (const float*)d_in[9];
  const float* Wo  = (const float*)d_in[10];
  const float* bo  = (const float*)d_in[11];
  const float* Wd1 = (const float*)d_in[12];
  const float* bd1 = (const float*)d_in[13];
  const float* Wd2 = (const float*)d_in[14];
  const float* bd2 = (const float*)d_in[15];
  float* out = (float*)d_out;

  const size_t WS_COUNTS  = 0;
  const size_t WS_CURSORS = 32;
  const size_t WS_TOPK    = 1024;
  const size_t WS_PLIST   = WS_TOPK  + (size_t)N_PTS*16;
  const size_t WS_PW      = WS_PLIST + (size_t)N_PTS*8;
  const size_t WS_PW0     = WS_PW    + (size_t)N_PTS*8;
  const size_t WS_PWH     = WS_PW0   + (size_t)8*8192;
  const size_t WS_PWO     = WS_PWH   + (size_t)24*139264;
  const size_t WS_PWD1    = WS_PWO   + (size_t)8*139264;
  const size_t WS_OUT     = WS_PWD1  + (size_t)139264;
  const size_t WS_END     = WS_OUT   + (size_t)2*N_PTS*256*2;

  if (ws_size < WS_END) {
    hipMemsetAsync(d_out, 0xFF, (size_t)out_size*4, stream);
    return;
  }

  uint8_t* ws = (uint8_t*)d_ws;
  uint32_t* counts  = (uint32_t*)(ws + WS_COUNTS);
  uint32_t* cursors = (uint32_t*)(ws + WS_CURSORS);
  uint4*    topk    = (uint4*)   (ws + WS_TOPK);
  uint32_t* plist   = (uint32_t*)(ws + WS_PLIST);
  float*    pw      = (float*)   (ws + WS_PW);
  short*    pW0     = (short*)   (ws + WS_PW0);
  short*    pWh     = (short*)   (ws + WS_PWH);
  short*    pWo     = (short*)   (ws + WS_PWO);
  short*    pWd1    = (short*)   (ws + WS_PWD1);
  short*    outbuf  = (short*)   (ws + WS_OUT);

  hipMemsetAsync(counts, 0, 64, stream);   // counts[8] + cursors[8]

  setup_kernel  <<<825,  512, 0, stream>>>(W0, b0, Wh, bh, Wo, bo, Wd1, bd1,
                                           pW0, pWh, pWo, pWd1,
                                           ctx, Wr1, br1, Wr2, br2, topk, counts);
  scatter_kernel<<<512,  256, 0, stream>>>(topk, counts, cursors, plist, pw);
  expert_kernel <<<4104, 256, 0, stream>>>(x, counts, plist, pw,
                                           pW0, pWh, pWo, outbuf);
  decoder_kernel<<<2048, 256, 0, stream>>>(outbuf, pWd1, Wd2, bd2, out);
}